// Round 9
// baseline (947.611 us; speedup 1.0000x reference)
//
#include <hip/hip_runtime.h>

typedef unsigned short u16;
typedef float f32x4 __attribute__((ext_vector_type(4)));
typedef __bf16 bf16x8 __attribute__((ext_vector_type(8)));

#define AS1 __attribute__((address_space(1)))
#define AS3 __attribute__((address_space(3)))

__device__ __forceinline__ float bf2f(u16 h) {
  return __uint_as_float(((unsigned)h) << 16);
}
__device__ __forceinline__ u16 f2bf(float f) {
  unsigned u = __float_as_uint(f);
  unsigned r = (u + 0x7FFFu + ((u >> 16) & 1u)) >> 16;
  return (u16)r;
}
__device__ __forceinline__ void gload16(const u16* g, u16* l) {
  __builtin_amdgcn_global_load_lds((const AS1 void*)g, (AS3 void*)l, 16, 0, 0);
}

// ---------------------------------------------------------------- transpose
// out[C,R] = bf16(in[R,C]^T), in fp32; R,C multiples of 32
__global__ void transpose_k(const float* __restrict__ in, u16* __restrict__ out,
                            int R, int C) {
  __shared__ u16 t[32][33];
  int c0 = blockIdx.x * 32, r0 = blockIdx.y * 32;
  int tx = threadIdx.x & 31, ty = threadIdx.x >> 5; // 32 x 8
  for (int i = 0; i < 32; i += 8)
    t[ty + i][tx] = f2bf(in[(size_t)(r0 + ty + i) * C + c0 + tx]);
  __syncthreads();
  for (int i = 0; i < 32; i += 8)
    out[(size_t)(c0 + ty + i) * R + r0 + tx] = t[tx][ty + i];
}

// four 768x768 weight transposes in one launch (z selects)
__global__ void transpose4_k(const float* __restrict__ s0, const float* __restrict__ s1,
                             const float* __restrict__ s2, const float* __restrict__ s3,
                             u16* __restrict__ d0, u16* __restrict__ d1,
                             u16* __restrict__ d2, u16* __restrict__ d3) {
  __shared__ u16 t[32][33];
  const float* in = (blockIdx.z == 0) ? s0 : (blockIdx.z == 1) ? s1
                    : (blockIdx.z == 2) ? s2 : s3;
  u16* out = (blockIdx.z == 0) ? d0 : (blockIdx.z == 1) ? d1
             : (blockIdx.z == 2) ? d2 : d3;
  int c0 = blockIdx.x * 32, r0 = blockIdx.y * 32;
  int tx = threadIdx.x & 31, ty = threadIdx.x >> 5;
  for (int i = 0; i < 32; i += 8)
    t[ty + i][tx] = f2bf(in[(size_t)(r0 + ty + i) * 768 + c0 + tx]);
  __syncthreads();
  for (int i = 0; i < 32; i += 8)
    out[(size_t)(c0 + ty + i) * 768 + r0 + tx] = t[tx][ty + i];
}

// pack bq|bk|bv -> bqkv[2304] fp32
__global__ void pack3_k(const float* __restrict__ a, const float* __restrict__ b,
                        const float* __restrict__ c, float* __restrict__ out) {
  int i = blockIdx.x * 256 + threadIdx.x;
  float v = (i < 768) ? a[i] : (i < 1536) ? b[i - 768] : c[i - 1536];
  out[i] = v;
}

// V columns of fused qkv [16384, 2304] -> VT [bh][96][1024]
#define QLD 2304
__global__ void vtrans_k(const u16* __restrict__ qkv, u16* __restrict__ vt) {
  __shared__ u16 t[32][33];
  int bh = blockIdx.z, b = bh >> 3, h = bh & 7;
  int n0 = blockIdx.y * 32, d0 = blockIdx.x * 32;
  int tx = threadIdx.x & 31, ty = threadIdx.x >> 5;
  const u16* src = qkv + (size_t)(b * 1024) * QLD + 1536 + h * 96;
  for (int i = 0; i < 32; i += 8)
    t[ty + i][tx] = src[(size_t)(n0 + ty + i) * QLD + d0 + tx];
  __syncthreads();
  u16* dst = vt + ((size_t)bh * 96 + d0) * 1024 + n0;
  for (int i = 0; i < 32; i += 8)
    dst[(size_t)(ty + i) * 1024 + tx] = t[tx][ty + i];
}

// ---------------------------------------------------------------- layernorm
// fp32 x -> bf16 out; gamma/beta fp32
__global__ __launch_bounds__(256) void ln_f32_k(const float* __restrict__ x,
                                                const float* __restrict__ gamma,
                                                const float* __restrict__ beta,
                                                u16* __restrict__ out) {
  __shared__ float red[8];
  int row = blockIdx.x, t = threadIdx.x;
  const float* xr = x + (size_t)row * 768;
  float v[3], s = 0.f, s2 = 0.f;
#pragma unroll
  for (int i = 0; i < 3; i++) {
    v[i] = xr[t + i * 256];
    s += v[i]; s2 += v[i] * v[i];
  }
#pragma unroll
  for (int off = 1; off < 64; off <<= 1) {
    s += __shfl_xor(s, off, 64);
    s2 += __shfl_xor(s2, off, 64);
  }
  int w = t >> 6;
  if ((t & 63) == 0) { red[w] = s; red[4 + w] = s2; }
  __syncthreads();
  s = red[0] + red[1] + red[2] + red[3];
  s2 = red[4] + red[5] + red[6] + red[7];
  float mu = s * (1.f / 768.f);
  float var = s2 * (1.f / 768.f) - mu * mu;
  float rs = rsqrtf(var + 1e-5f);
  u16* orow = out + (size_t)row * 768;
#pragma unroll
  for (int i = 0; i < 3; i++) {
    int c = t + i * 256;
    orow[c] = f2bf((v[i] - mu) * rs * gamma[c] + beta[c]);
  }
}

// ---------------------------------------------------------------- GEMM 128x128
// EPI 0: C=bf16(A@Bt^T + bias)
// EPI 2: C=bf16(gelu(A@Bt^T + bias))
// EPI 4: C=fp32(A@Bt^T + bias + res_fp32)   (res may alias C 1:1)
// Triple-buffered BK=32 (48KB LDS -> 3 blocks/CU), prefetch distance 2
// (vmcnt(8)), fragment-major LDS subtiles, XCD swizzle. Used for the
// long-K FFN2 (K=3072, NT=96) where this structure is near its best.
#define BM 128
#define BN 128
#define BK 32

template <int EPI>
__global__ __launch_bounds__(256, 3) void gemm_bt(
    const u16* __restrict__ A, const u16* __restrict__ Bt,
    const float* __restrict__ bias, const float* __restrict__ res,
    void* __restrict__ Cv, int M, int N, int K, int lda) {
  __shared__ u16 As[3][BM * BK];
  __shared__ u16 Bs[3][BN * BK];
  int tid = threadIdx.x, lane = tid & 63, w = tid >> 6;
  int l15 = lane & 15, quad = lane >> 4;
  int wm = (w >> 1) * 64, wn = (w & 1) * 64;
  int GX = gridDim.x;
  int f = blockIdx.y * GX + blockIdx.x;
  int mpx = GX >> 3;
  int xcd = f & 7, idx = f >> 3;
  int m0 = (xcd * mpx + (idx % mpx)) * BM;
  int n0 = (idx / mpx) * BN;
  int NT = K / BK;
#pragma unroll
  for (int pt = 0; pt < 2; pt++) {
#pragma unroll
    for (int i = 0; i < 2; i++) {
      int c = w * 2 + i;
      int r = c * 16 + l15, col = pt * BK + quad * 8;
      gload16(A + (size_t)(m0 + r) * lda + col, As[pt] + c * 512);
      gload16(Bt + (size_t)(n0 + r) * K + col, Bs[pt] + c * 512);
    }
  }
  f32x4 acc[4][4] = {};
  for (int t = 0; t < NT; t++) {
    int cur = t % 3, nx = (t + 2) % 3;
    __builtin_amdgcn_s_barrier();
    int k0 = (t + 2 < NT) ? (t + 2) * BK : 0;
#pragma unroll
    for (int i = 0; i < 2; i++) {
      int c = w * 2 + i;
      int r = c * 16 + l15, col = quad * 8;
      gload16(A + (size_t)(m0 + r) * lda + k0 + col, As[nx] + c * 512);
      gload16(Bt + (size_t)(n0 + r) * K + k0 + col, Bs[nx] + c * 512);
    }
    asm volatile("s_waitcnt vmcnt(8)" ::: "memory");
    __builtin_amdgcn_s_barrier();
    const u16* ab = As[cur];
    const u16* bb = Bs[cur];
    bf16x8 af[4], bfv[4];
#pragma unroll
    for (int i = 0; i < 4; i++) {
      af[i] = *(const bf16x8*)(ab + ((w >> 1) * 4 + i) * 512 + lane * 8);
      bfv[i] = *(const bf16x8*)(bb + ((w & 1) * 4 + i) * 512 + lane * 8);
    }
#pragma unroll
    for (int mt = 0; mt < 4; mt++)
#pragma unroll
      for (int nt = 0; nt < 4; nt++)
        acc[mt][nt] = __builtin_amdgcn_mfma_f32_16x16x32_bf16(
            af[mt], bfv[nt], acc[mt][nt], 0, 0, 0);
  }
  asm volatile("s_waitcnt vmcnt(0)" ::: "memory");
#pragma unroll
  for (int nt = 0; nt < 4; nt++) {
    int col = n0 + wn + nt * 16 + l15;
    float bv = bias[col];
#pragma unroll
    for (int mt = 0; mt < 4; mt++) {
      int row = m0 + wm + mt * 16 + quad * 4;
#pragma unroll
      for (int r = 0; r < 4; r++) {
        float v = acc[mt][nt][r] + bv;
        size_t idx2 = (size_t)(row + r) * N + col;
        if (EPI == 4) {
          v += res[idx2];
          ((float*)Cv)[idx2] = v;
        } else {
          if (EPI == 2) v = 0.5f * v * (1.0f + erff(v * 0.70710678118654752f));
          ((u16*)Cv)[idx2] = f2bf(v);
        }
      }
    }
  }
}

// ---------------------------------------------------------------- GEMM 256x64
// R9: big-M tile for the short-K GEMMs (QKV, Wo, FFN1 at K=768):
//   256x64 tile, 4 waves (wave w owns rows w*64..+63, all 64 cols),
//   BK=64 double-buffer = exactly 80KB LDS -> 2 blocks/CU (160KB).
//   2x MFMA per barrier-pair vs 128x128/BK32; grids are exact multiples
//   of 256 (QKV (64,36), Wo (64,12), FFN1 (32,48)) -> zero CU tail.
//   Fragment-major 1KB subtile blocks (conflict-free contiguous wave
//   reads; global source pre-permuted per m173). Counted vmcnt(10):
//   staging = 10 gload16/thread/K-tile (A:8, B:2), never drained to 0
//   inside the loop. XCD swizzle (gridDim.x % 8 == 0).
template <int EPI>
__global__ __launch_bounds__(256, 2) void gemm256_bt(
    const u16* __restrict__ A, const u16* __restrict__ Bt,
    const float* __restrict__ bias, const float* __restrict__ res,
    void* __restrict__ Cv, int M, int N, int K, int lda) {
  __shared__ u16 As[2][256 * 64];   // 32 subtiles of 1KB per buffer
  __shared__ u16 Bs[2][64 * 64];    // 8 subtiles of 1KB per buffer
  int tid = threadIdx.x, lane = tid & 63, w = tid >> 6;
  int l15 = lane & 15, quad = lane >> 4;
  int GX = gridDim.x;
  int f = blockIdx.y * GX + blockIdx.x;
  int mpx = GX >> 3;
  int xcd = f & 7, idx = f >> 3;
  int m0 = (xcd * mpx + (idx % mpx)) * 256;
  int n0 = (idx / mpx) * 64;
  int NT = K / 64;
  // staging coords: A chunk c (0..31): rows (c>>1)*16+l15, col half c&1;
  // wave w stages A chunks w*8..w*8+7 and B chunks w*2..w*2+1
  // prologue: stage tile 0
#pragma unroll
  for (int i = 0; i < 8; i++) {
    int c = w * 8 + i;
    gload16(A + (size_t)(m0 + (c >> 1) * 16 + l15) * lda + (c & 1) * 32 + quad * 8,
            As[0] + c * 512);
  }
#pragma unroll
  for (int i = 0; i < 2; i++) {
    int c = w * 2 + i;
    gload16(Bt + (size_t)(n0 + (c >> 1) * 16 + l15) * K + (c & 1) * 32 + quad * 8,
            Bs[0] + c * 512);
  }
  f32x4 acc[4][4] = {};
  for (int t = 0; t < NT; t++) {
    int cur = t & 1;
    // barrier 1: all waves done reading buf[cur^1] (previous iteration)
    __builtin_amdgcn_s_barrier();
    int k0 = (t + 1 < NT) ? (t + 1) * 64 : 0;  // wraparound: harmless restage
#pragma unroll
    for (int i = 0; i < 8; i++) {
      int c = w * 8 + i;
      gload16(A + (size_t)(m0 + (c >> 1) * 16 + l15) * lda + k0 + (c & 1) * 32 + quad * 8,
              As[cur ^ 1] + c * 512);
    }
#pragma unroll
    for (int i = 0; i < 2; i++) {
      int c = w * 2 + i;
      gload16(Bt + (size_t)(n0 + (c >> 1) * 16 + l15) * K + k0 + (c & 1) * 32 + quad * 8,
              Bs[cur ^ 1] + c * 512);
    }
    // wait ONLY the previous tile's 10 loads; ours stay in flight
    asm volatile("s_waitcnt vmcnt(10)" ::: "memory");
    __builtin_amdgcn_s_barrier();
    const u16* ab = As[cur];
    const u16* bb = Bs[cur];
#pragma unroll
    for (int kk = 0; kk < 2; kk++) {
      bf16x8 af[4], bfv[4];
#pragma unroll
      for (int i = 0; i < 4; i++) {
        af[i] = *(const bf16x8*)(ab + ((w * 4 + i) * 2 + kk) * 512 + lane * 8);
        bfv[i] = *(const bf16x8*)(bb + (i * 2 + kk) * 512 + lane * 8);
      }
#pragma unroll
      for (int mt = 0; mt < 4; mt++)
#pragma unroll
        for (int nt = 0; nt < 4; nt++)
          acc[mt][nt] = __builtin_amdgcn_mfma_f32_16x16x32_bf16(
              af[mt], bfv[nt], acc[mt][nt], 0, 0, 0);
    }
  }
  // drain dangling wraparound prefetch (LDS writes must land before exit)
  asm volatile("s_waitcnt vmcnt(0)" ::: "memory");
  // epilogue: C/D layout col=lane&15, row=quad*4+reg
#pragma unroll
  for (int nt = 0; nt < 4; nt++) {
    int col = n0 + nt * 16 + l15;
    float bv = bias[col];
#pragma unroll
    for (int mt = 0; mt < 4; mt++) {
      int row = m0 + w * 64 + mt * 16 + quad * 4;
#pragma unroll
      for (int r = 0; r < 4; r++) {
        float v = acc[mt][nt][r] + bv;
        size_t idx2 = (size_t)(row + r) * N + col;
        if (EPI == 4) {
          v += res[idx2];
          ((float*)Cv)[idx2] = v;
        } else {
          if (EPI == 2) v = 0.5f * v * (1.0f + erff(v * 0.70710678118654752f));
          ((u16*)Cv)[idx2] = f2bf(v);
        }
      }
    }
  }
}

// ---------------------------------------------------------------- attention
// flash-style on fused qkv [16384,2304] (q cols 0..767, k cols 768..1535);
// vt: [bh][96][1024]; OUTPUT to separate dense [16384,768] buffer (R5
// lesson: strided output = 8x write amplification; reads are fine).
// R1: padded LDS strides. R2/R3: 2-phase schedule, double-buffered ks/vts,
// wraparound reg prefetch, ONE barrier/kt. R4: XCD swizzle; per-lane
// partial li; scale folded into exp args.
#define QSS 104
#define VSS 72
#define PSS 72
__global__ __launch_bounds__(256, 2) void attn_k(const u16* __restrict__ qkv,
                                                 const u16* __restrict__ vt,
                                                 u16* __restrict__ o) {
  __shared__ u16 qs[64 * QSS];
  __shared__ u16 ks[2][64 * QSS];
  __shared__ u16 vts[2][96 * VSS];
  __shared__ u16 ps[4 * 16 * PSS];
  int tid = threadIdx.x, lane = tid & 63, w = tid >> 6;
  int l15 = lane & 15, quad = lane >> 4;
  int f = blockIdx.y * 16 + blockIdx.x;
  int xcd = f & 7, idx = f >> 3;
  int bh = xcd * 16 + (idx & 15);
  int qt = idx >> 4;
  int b = bh >> 3, h = bh & 7;
  const u16* qbase = qkv + (size_t)(b * 1024 + qt * 64) * QLD + h * 96;
  const u16* kbase = qkv + (size_t)(b * 1024) * QLD + 768 + h * 96;
  const u16* vtbase = vt + (size_t)bh * 96 * 1024;
  int kr[3], ko[3], vr[3], vo[3];
#pragma unroll
  for (int i = 0; i < 3; i++) {
    int c = tid + i * 256;
    kr[i] = c / 12; ko[i] = (c % 12) * 8;
    vr[i] = c >> 3; vo[i] = (c & 7) * 8;
  }
#pragma unroll
  for (int i = 0; i < 3; i++)
    *(uint4*)(qs + kr[i] * QSS + ko[i]) =
        *(const uint4*)(qbase + (size_t)kr[i] * QLD + ko[i]);
  uint4 kreg[3], vreg[3];
#pragma unroll
  for (int i = 0; i < 3; i++) {
    kreg[i] = *(const uint4*)(kbase + (size_t)kr[i] * QLD + ko[i]);
    vreg[i] = *(const uint4*)(vtbase + (size_t)vr[i] * 1024 + vo[i]);
  }
#pragma unroll
  for (int i = 0; i < 3; i++) {
    *(uint4*)(ks[0] + kr[i] * QSS + ko[i]) = kreg[i];
    *(uint4*)(vts[0] + vr[i] * VSS + vo[i]) = vreg[i];
  }
  __syncthreads();

  float mi[4], li[4];
#pragma unroll
  for (int r = 0; r < 4; r++) { mi[r] = -1e30f; li[r] = 0.f; }
  f32x4 oacc[6] = {};
  const float scale = 0.10206207261596577f; // 1/sqrt(96)
  for (int kt = 0; kt < 16; kt++) {
    int cur = kt & 1, nxt = cur ^ 1;
    int ktn = (kt + 1) & 15;
#pragma unroll
    for (int i = 0; i < 3; i++) {
      kreg[i] = *(const uint4*)(kbase + (size_t)(ktn * 64 + kr[i]) * QLD + ko[i]);
      vreg[i] = *(const uint4*)(vtbase + (size_t)vr[i] * 1024 + ktn * 64 + vo[i]);
    }
    f32x4 s[4] = {};
#pragma unroll
    for (int kk = 0; kk < 3; kk++) {
      bf16x8 a = *(const bf16x8*)(qs + (w * 16 + l15) * QSS + kk * 32 + quad * 8);
#pragma unroll
      for (int nt = 0; nt < 4; nt++) {
        bf16x8 bb =
            *(const bf16x8*)(ks[cur] + (nt * 16 + l15) * QSS + kk * 32 + quad * 8);
        s[nt] = __builtin_amdgcn_mfma_f32_16x16x32_bf16(a, bb, s[nt], 0, 0, 0);
      }
    }
#pragma unroll
    for (int r = 0; r < 4; r++) {
      float sv[4], mx = -1e30f;
#pragma unroll
      for (int nt = 0; nt < 4; nt++) {
        sv[nt] = s[nt][r];
        mx = fmaxf(mx, sv[nt]);
      }
#pragma unroll
      for (int off = 1; off < 16; off <<= 1) mx = fmaxf(mx, __shfl_xor(mx, off, 16));
      float mnew = fmaxf(mi[r], mx);
      float alpha = __expf((mi[r] - mnew) * scale);
      float rs = 0.f;
#pragma unroll
      for (int nt = 0; nt < 4; nt++) {
        sv[nt] = __expf((sv[nt] - mnew) * scale);
        rs += sv[nt];
      }
      li[r] = li[r] * alpha + rs;
      mi[r] = mnew;
#pragma unroll
      for (int ht = 0; ht < 6; ht++) oacc[ht][r] *= alpha;
      int prow = quad * 4 + r;
#pragma unroll
      for (int nt = 0; nt < 4; nt++)
        ps[w * 16 * PSS + prow * PSS + nt * 16 + l15] = f2bf(sv[nt]);
    }
    asm volatile("s_waitcnt lgkmcnt(0)" ::: "memory");
#pragma unroll
    for (int kk = 0; kk < 2; kk++) {
      bf16x8 a = *(const bf16x8*)(ps + w * 16 * PSS + l15 * PSS + kk * 32 + quad * 8);
#pragma unroll
      for (int ht = 0; ht < 6; ht++) {
        bf16x8 bb =
            *(const bf16x8*)(vts[cur] + (ht * 16 + l15) * VSS + kk * 32 + quad * 8);
        oacc[ht] = __builtin_amdgcn_mfma_f32_16x16x32_bf16(a, bb, oacc[ht], 0, 0, 0);
      }
    }
#pragma unroll
    for (int i = 0; i < 3; i++) {
      *(uint4*)(ks[nxt] + kr[i] * QSS + ko[i]) = kreg[i];
      *(uint4*)(vts[nxt] + vr[i] * VSS + vo[i]) = vreg[i];
    }
    __syncthreads();
  }
#pragma unroll
  for (int r = 0; r < 4; r++)
#pragma unroll
    for (int off = 1; off < 16; off <<= 1) li[r] += __shfl_xor(li[r], off, 16);
  u16* obase = o + (size_t)(b * 1024 + qt * 64 + w * 16) * 768 + h * 96;
#pragma unroll
  for (int r = 0; r < 4; r++) {
    float inv = 1.0f / li[r];
    int row = quad * 4 + r;
#pragma unroll
    for (int ht = 0; ht < 6; ht++)
      obase[(size_t)row * 768 + ht * 16 + l15] = f2bf(oacc[ht][r] * inv);
  }
}

// ---------------------------------------------------------------- launch
// d_out timeline: vtrans writes VT into d_out -> attn reads it -> Wo-GEMM
// overwrites d_out with y1 (VT dead) -> FFN2 reads res=y1, writes 1:1.
// ws: weights 14.2MB + bqkv + hb 25.2MB + qkvb 75.5MB ~= 115MB (proven).
extern "C" void kernel_launch(void* const* d_in, const int* in_sizes, int n_in,
                              void* d_out, int out_size, void* d_ws,
                              size_t ws_size, hipStream_t stream) {
  const float* x = (const float*)d_in[0];
  const float* gamma = (const float*)d_in[1];
  const float* beta = (const float*)d_in[2];
  const float* Wq = (const float*)d_in[3];
  const float* bq = (const float*)d_in[4];
  const float* Wk = (const float*)d_in[5];
  const float* bk = (const float*)d_in[6];
  const float* Wv = (const float*)d_in[7];
  const float* bv = (const float*)d_in[8];
  const float* Wo = (const float*)d_in[9];
  const float* bo = (const float*)d_in[10];
  const float* W1 = (const float*)d_in[11];
  const float* b1 = (const float*)d_in[12];
  const float* W2 = (const float*)d_in[13];
  const float* b2 = (const float*)d_in[14];
  float* out = (float*)d_out;

  char* ws = (char*)d_ws;
  size_t off = 0;
  auto alloc = [&](size_t elems) {
    u16* p = (u16*)(ws + off);
    off += elems * sizeof(u16);
    return p;
  };
  u16* WqT = alloc(768 * 768);   // WqT|WkT|WvT adjacent = fused [2304,768]
  u16* WkT = alloc(768 * 768);
  u16* WvT = alloc(768 * 768);
  u16* WoT = alloc(768 * 768);
  u16* W1T = alloc((size_t)768 * 3072);    // [3072,768]
  u16* W2T = alloc((size_t)3072 * 768);    // [768,3072]
  float* bqkv = (float*)(ws + off); off += 2304 * sizeof(float);
  u16* hb = alloc((size_t)16384 * 768);    // h -> attn_out -> h2
  u16* qkvb = alloc((size_t)16384 * 2304); // qkv -> f-chunks
  u16* vtb = (u16*)d_out;                  // VT lives in d_out until Wo

  // weight transposes fp32 -> bf16 [N,K]
  transpose4_k<<<dim3(24, 24, 4), 256, 0, stream>>>(Wq, Wk, Wv, Wo,
                                                    WqT, WkT, WvT, WoT);
  transpose_k<<<dim3(96, 24), 256, 0, stream>>>(W1, W1T, 768, 3072);
  transpose_k<<<dim3(24, 96), 256, 0, stream>>>(W2, W2T, 3072, 768);
  pack3_k<<<9, 256, 0, stream>>>(bq, bk, bv, bqkv);

  // LN1: x(fp32) -> h(bf16)
  ln_f32_k<<<16384, 256, 0, stream>>>(x, gamma, beta, hb);
  // fused QKV projection: [16384,768] @ [2304,768]^T -> qkvb [16384,2304]
  gemm256_bt<0><<<dim3(64, 36), 256, 0, stream>>>(hb, WqT, bqkv, nullptr,
                                                  qkvb, 16384, 2304, 768, 768);
  // V cols -> VT [bh][96][1024] into d_out
  vtrans_k<<<dim3(3, 32, 128), 256, 0, stream>>>(qkvb, vtb);
  // attention: q,k from qkvb + VT from d_out -> dense attn-out in hb
  attn_k<<<dim3(16, 128), 256, 0, stream>>>(qkvb, vtb, hb);
  // y1(fp32, in d_out) = attn_out @ Wo + bo + x  (overwrites VT - dead)
  gemm256_bt<4><<<dim3(64, 12), 256, 0, stream>>>(hb, WoT, bo, x, out,
                                                  16384, 768, 768, 768);
  // h2 = LN(y1) -> hb (attn-out dead)
  ln_f32_k<<<16384, 256, 0, stream>>>(out, gamma, beta, hb);
  // FFN in 2 M-chunks of 8192 rows; f-chunk [8192,3072] bf16 fits qkvb
  for (int c = 0; c < 2; c++) {
    const u16* h2c = hb + (size_t)c * 8192 * 768;
    const float* y1c = out + (size_t)c * 8192 * 768;
    float* outc = out + (size_t)c * 8192 * 768;
    gemm256_bt<2><<<dim3(32, 48), 256, 0, stream>>>(h2c, W1T, b1, nullptr,
                                                    qkvb, 8192, 3072, 768, 768);
    gemm_bt<4><<<dim3(64, 6), 256, 0, stream>>>(qkvb, W2T, b2, y1c, outc,
                                                8192, 768, 3072, 3072);
  }
}

// Round 10
// 838.032 us; speedup vs baseline: 1.1308x; 1.1308x over previous
//
#include <hip/hip_runtime.h>

typedef unsigned short u16;
typedef float f32x4 __attribute__((ext_vector_type(4)));
typedef __bf16 bf16x8 __attribute__((ext_vector_type(8)));

#define AS1 __attribute__((address_space(1)))
#define AS3 __attribute__((address_space(3)))

__device__ __forceinline__ float bf2f(u16 h) {
  return __uint_as_float(((unsigned)h) << 16);
}
__device__ __forceinline__ u16 f2bf(float f) {
  unsigned u = __float_as_uint(f);
  unsigned r = (u + 0x7FFFu + ((u >> 16) & 1u)) >> 16;
  return (u16)r;
}
__device__ __forceinline__ void gload16(const u16* g, u16* l) {
  __builtin_amdgcn_global_load_lds((const AS1 void*)g, (AS3 void*)l, 16, 0, 0);
}

// ---------------------------------------------------------------- transpose
// out[C,R] = bf16(in[R,C]^T), in fp32; R,C multiples of 32
__global__ void transpose_k(const float* __restrict__ in, u16* __restrict__ out,
                            int R, int C) {
  __shared__ u16 t[32][33];
  int c0 = blockIdx.x * 32, r0 = blockIdx.y * 32;
  int tx = threadIdx.x & 31, ty = threadIdx.x >> 5; // 32 x 8
  for (int i = 0; i < 32; i += 8)
    t[ty + i][tx] = f2bf(in[(size_t)(r0 + ty + i) * C + c0 + tx]);
  __syncthreads();
  for (int i = 0; i < 32; i += 8)
    out[(size_t)(c0 + ty + i) * R + r0 + tx] = t[tx][ty + i];
}

// four 768x768 weight transposes in one launch (z selects)
__global__ void transpose4_k(const float* __restrict__ s0, const float* __restrict__ s1,
                             const float* __restrict__ s2, const float* __restrict__ s3,
                             u16* __restrict__ d0, u16* __restrict__ d1,
                             u16* __restrict__ d2, u16* __restrict__ d3) {
  __shared__ u16 t[32][33];
  const float* in = (blockIdx.z == 0) ? s0 : (blockIdx.z == 1) ? s1
                    : (blockIdx.z == 2) ? s2 : s3;
  u16* out = (blockIdx.z == 0) ? d0 : (blockIdx.z == 1) ? d1
             : (blockIdx.z == 2) ? d2 : d3;
  int c0 = blockIdx.x * 32, r0 = blockIdx.y * 32;
  int tx = threadIdx.x & 31, ty = threadIdx.x >> 5;
  for (int i = 0; i < 32; i += 8)
    t[ty + i][tx] = f2bf(in[(size_t)(r0 + ty + i) * 768 + c0 + tx]);
  __syncthreads();
  for (int i = 0; i < 32; i += 8)
    out[(size_t)(c0 + ty + i) * 768 + r0 + tx] = t[tx][ty + i];
}

// pack bq|bk|bv -> bqkv[2304] fp32
__global__ void pack3_k(const float* __restrict__ a, const float* __restrict__ b,
                        const float* __restrict__ c, float* __restrict__ out) {
  int i = blockIdx.x * 256 + threadIdx.x;
  float v = (i < 768) ? a[i] : (i < 1536) ? b[i - 768] : c[i - 1536];
  out[i] = v;
}

// V columns of fused qkv [16384, 2304] -> VT [bh][96][1024]
#define QLD 2304
__global__ void vtrans_k(const u16* __restrict__ qkv, u16* __restrict__ vt) {
  __shared__ u16 t[32][33];
  int bh = blockIdx.z, b = bh >> 3, h = bh & 7;
  int n0 = blockIdx.y * 32, d0 = blockIdx.x * 32;
  int tx = threadIdx.x & 31, ty = threadIdx.x >> 5;
  const u16* src = qkv + (size_t)(b * 1024) * QLD + 1536 + h * 96;
  for (int i = 0; i < 32; i += 8)
    t[ty + i][tx] = src[(size_t)(n0 + ty + i) * QLD + d0 + tx];
  __syncthreads();
  u16* dst = vt + ((size_t)bh * 96 + d0) * 1024 + n0;
  for (int i = 0; i < 32; i += 8)
    dst[(size_t)(ty + i) * 1024 + tx] = t[tx][ty + i];
}

// ---------------------------------------------------------------- layernorm
// fp32 x -> bf16 out; gamma/beta fp32
__global__ __launch_bounds__(256) void ln_f32_k(const float* __restrict__ x,
                                                const float* __restrict__ gamma,
                                                const float* __restrict__ beta,
                                                u16* __restrict__ out) {
  __shared__ float red[8];
  int row = blockIdx.x, t = threadIdx.x;
  const float* xr = x + (size_t)row * 768;
  float v[3], s = 0.f, s2 = 0.f;
#pragma unroll
  for (int i = 0; i < 3; i++) {
    v[i] = xr[t + i * 256];
    s += v[i]; s2 += v[i] * v[i];
  }
#pragma unroll
  for (int off = 1; off < 64; off <<= 1) {
    s += __shfl_xor(s, off, 64);
    s2 += __shfl_xor(s2, off, 64);
  }
  int w = t >> 6;
  if ((t & 63) == 0) { red[w] = s; red[4 + w] = s2; }
  __syncthreads();
  s = red[0] + red[1] + red[2] + red[3];
  s2 = red[4] + red[5] + red[6] + red[7];
  float mu = s * (1.f / 768.f);
  float var = s2 * (1.f / 768.f) - mu * mu;
  float rs = rsqrtf(var + 1e-5f);
  u16* orow = out + (size_t)row * 768;
#pragma unroll
  for (int i = 0; i < 3; i++) {
    int c = t + i * 256;
    orow[c] = f2bf((v[i] - mu) * rs * gamma[c] + beta[c]);
  }
}

// ---------------------------------------------------------------- GEMM
// EPI 0: C=bf16(A@Bt^T + bias)
// EPI 2: C=bf16(gelu(A@Bt^T + bias))
// EPI 4: C=fp32(A@Bt^T + bias + res_fp32)   (res may alias C 1:1)
// R10 = R4's occupancy x R9's conflict-free layout:
//   128x128 tile, BK=64, SINGLE 32KB LDS buffer -> 5 blocks/CU at
//   VGPR~88 (20 waves/CU). The __syncthreads vmcnt(0) drain is covered
//   by the other resident blocks (m114 wave-level overlap) — R6-R9
//   proved explicit multi-buffering loses more occupancy than it gains.
//   Fragment-major 1KB subtiles: subtile c (row-group c>>1, col-half
//   c&1) stored contiguously in exactly the wave's MFMA read order, so
//   every ds_read_b128 is a contiguous 1KB wave read = 0 conflicts
//   (global source pre-permuted per m173; proven R5-R9).
//   XCD-aware block swizzle (gridDim.x % 8 == 0).
#define BM 128
#define BN 128
#define BK 64

template <int EPI>
__global__ __launch_bounds__(256, 4) void gemm_bt(
    const u16* __restrict__ A, const u16* __restrict__ Bt,
    const float* __restrict__ bias, const float* __restrict__ res,
    void* __restrict__ Cv, int M, int N, int K, int lda) {
  __shared__ u16 As[BM * BK];   // 16 subtiles x 1KB
  __shared__ u16 Bs[BN * BK];
  int tid = threadIdx.x, lane = tid & 63, w = tid >> 6;
  int l15 = lane & 15, quad = lane >> 4;
  int wm = (w >> 1) * 64, wn = (w & 1) * 64;
  // XCD-aware swizzle: f = HW linear block id (x fastest)
  int GX = gridDim.x;
  int f = blockIdx.y * GX + blockIdx.x;
  int mpx = GX >> 3;
  int xcd = f & 7, idx = f >> 3;
  int m0 = (xcd * mpx + (idx % mpx)) * BM;
  int n0 = (idx / mpx) * BN;
  int NT = K / BK;
  // staging: chunk c = w*4+i (c in 0..15): row (c>>1)*16 + l15,
  // col (c&1)*32 + quad*8 — matches the fragment read order exactly.
  int sr[4], sc[4];
#pragma unroll
  for (int i = 0; i < 4; i++) {
    int c = w * 4 + i;
    sr[i] = (c >> 1) * 16 + l15;
    sc[i] = (c & 1) * 32 + quad * 8;
  }
  f32x4 acc[4][4] = {};
  for (int t = 0; t < NT; t++) {
    __syncthreads();               // prev iteration's reads done
    int k0 = t * BK;
#pragma unroll
    for (int i = 0; i < 4; i++) {
      int c = w * 4 + i;
      gload16(A + (size_t)(m0 + sr[i]) * lda + k0 + sc[i], As + c * 512);
      gload16(Bt + (size_t)(n0 + sr[i]) * K + k0 + sc[i], Bs + c * 512);
    }
    __syncthreads();               // vmcnt(0) drain + barrier: tile ready
#pragma unroll
    for (int kk = 0; kk < 2; kk++) {
      bf16x8 af[4], bfv[4];
#pragma unroll
      for (int i = 0; i < 4; i++) {
        int ga = (w >> 1) * 4 + i;       // A row-group for this wave
        int gb = (w & 1) * 4 + i;        // B row-group for this wave
        af[i] = *(const bf16x8*)(As + (ga * 2 + kk) * 512 + lane * 8);
        bfv[i] = *(const bf16x8*)(Bs + (gb * 2 + kk) * 512 + lane * 8);
      }
#pragma unroll
      for (int mt = 0; mt < 4; mt++)
#pragma unroll
        for (int nt = 0; nt < 4; nt++)
          acc[mt][nt] = __builtin_amdgcn_mfma_f32_16x16x32_bf16(
              af[mt], bfv[nt], acc[mt][nt], 0, 0, 0);
    }
  }
  // epilogue: C/D layout col=lane&15, row=quad*4+reg (m89/m91-verified)
#pragma unroll
  for (int nt = 0; nt < 4; nt++) {
    int col = n0 + wn + nt * 16 + l15;
    float bv = bias[col];
#pragma unroll
    for (int mt = 0; mt < 4; mt++) {
      int row = m0 + wm + mt * 16 + quad * 4;
#pragma unroll
      for (int r = 0; r < 4; r++) {
        float v = acc[mt][nt][r] + bv;
        size_t idx2 = (size_t)(row + r) * N + col;
        if (EPI == 4) {
          v += res[idx2];
          ((float*)Cv)[idx2] = v;
        } else {
          if (EPI == 2) v = 0.5f * v * (1.0f + erff(v * 0.70710678118654752f));
          ((u16*)Cv)[idx2] = f2bf(v);
        }
      }
    }
  }
}

// ---------------------------------------------------------------- attention
// flash-style on fused qkv [16384,2304] (q cols 0..767, k cols 768..1535);
// vt: [bh][96][1024]; OUTPUT to separate dense [16384,768] buffer (R5
// lesson: strided output = 8x write amplification; reads are fine).
// R1: padded LDS strides. R2/R3: 2-phase schedule, double-buffered ks/vts,
// wraparound reg prefetch, ONE barrier/kt. R4: XCD swizzle; per-lane
// partial li; scale folded into exp args.
#define QSS 104
#define VSS 72
#define PSS 72
__global__ __launch_bounds__(256, 2) void attn_k(const u16* __restrict__ qkv,
                                                 const u16* __restrict__ vt,
                                                 u16* __restrict__ o) {
  __shared__ u16 qs[64 * QSS];
  __shared__ u16 ks[2][64 * QSS];
  __shared__ u16 vts[2][96 * VSS];
  __shared__ u16 ps[4 * 16 * PSS];
  int tid = threadIdx.x, lane = tid & 63, w = tid >> 6;
  int l15 = lane & 15, quad = lane >> 4;
  int f = blockIdx.y * 16 + blockIdx.x;
  int xcd = f & 7, idx = f >> 3;
  int bh = xcd * 16 + (idx & 15);
  int qt = idx >> 4;
  int b = bh >> 3, h = bh & 7;
  const u16* qbase = qkv + (size_t)(b * 1024 + qt * 64) * QLD + h * 96;
  const u16* kbase = qkv + (size_t)(b * 1024) * QLD + 768 + h * 96;
  const u16* vtbase = vt + (size_t)bh * 96 * 1024;
  int kr[3], ko[3], vr[3], vo[3];
#pragma unroll
  for (int i = 0; i < 3; i++) {
    int c = tid + i * 256;
    kr[i] = c / 12; ko[i] = (c % 12) * 8;
    vr[i] = c >> 3; vo[i] = (c & 7) * 8;
  }
#pragma unroll
  for (int i = 0; i < 3; i++)
    *(uint4*)(qs + kr[i] * QSS + ko[i]) =
        *(const uint4*)(qbase + (size_t)kr[i] * QLD + ko[i]);
  uint4 kreg[3], vreg[3];
#pragma unroll
  for (int i = 0; i < 3; i++) {
    kreg[i] = *(const uint4*)(kbase + (size_t)kr[i] * QLD + ko[i]);
    vreg[i] = *(const uint4*)(vtbase + (size_t)vr[i] * 1024 + vo[i]);
  }
#pragma unroll
  for (int i = 0; i < 3; i++) {
    *(uint4*)(ks[0] + kr[i] * QSS + ko[i]) = kreg[i];
    *(uint4*)(vts[0] + vr[i] * VSS + vo[i]) = vreg[i];
  }
  __syncthreads();

  float mi[4], li[4];
#pragma unroll
  for (int r = 0; r < 4; r++) { mi[r] = -1e30f; li[r] = 0.f; }
  f32x4 oacc[6] = {};
  const float scale = 0.10206207261596577f; // 1/sqrt(96)
  for (int kt = 0; kt < 16; kt++) {
    int cur = kt & 1, nxt = cur ^ 1;
    int ktn = (kt + 1) & 15;
#pragma unroll
    for (int i = 0; i < 3; i++) {
      kreg[i] = *(const uint4*)(kbase + (size_t)(ktn * 64 + kr[i]) * QLD + ko[i]);
      vreg[i] = *(const uint4*)(vtbase + (size_t)vr[i] * 1024 + ktn * 64 + vo[i]);
    }
    f32x4 s[4] = {};
#pragma unroll
    for (int kk = 0; kk < 3; kk++) {
      bf16x8 a = *(const bf16x8*)(qs + (w * 16 + l15) * QSS + kk * 32 + quad * 8);
#pragma unroll
      for (int nt = 0; nt < 4; nt++) {
        bf16x8 bb =
            *(const bf16x8*)(ks[cur] + (nt * 16 + l15) * QSS + kk * 32 + quad * 8);
        s[nt] = __builtin_amdgcn_mfma_f32_16x16x32_bf16(a, bb, s[nt], 0, 0, 0);
      }
    }
#pragma unroll
    for (int r = 0; r < 4; r++) {
      float sv[4], mx = -1e30f;
#pragma unroll
      for (int nt = 0; nt < 4; nt++) {
        sv[nt] = s[nt][r];
        mx = fmaxf(mx, sv[nt]);
      }
#pragma unroll
      for (int off = 1; off < 16; off <<= 1) mx = fmaxf(mx, __shfl_xor(mx, off, 16));
      float mnew = fmaxf(mi[r], mx);
      float alpha = __expf((mi[r] - mnew) * scale);
      float rs = 0.f;
#pragma unroll
      for (int nt = 0; nt < 4; nt++) {
        sv[nt] = __expf((sv[nt] - mnew) * scale);
        rs += sv[nt];
      }
      li[r] = li[r] * alpha + rs;
      mi[r] = mnew;
#pragma unroll
      for (int ht = 0; ht < 6; ht++) oacc[ht][r] *= alpha;
      int prow = quad * 4 + r;
#pragma unroll
      for (int nt = 0; nt < 4; nt++)
        ps[w * 16 * PSS + prow * PSS + nt * 16 + l15] = f2bf(sv[nt]);
    }
    asm volatile("s_waitcnt lgkmcnt(0)" ::: "memory");
#pragma unroll
    for (int kk = 0; kk < 2; kk++) {
      bf16x8 a = *(const bf16x8*)(ps + w * 16 * PSS + l15 * PSS + kk * 32 + quad * 8);
#pragma unroll
      for (int ht = 0; ht < 6; ht++) {
        bf16x8 bb =
            *(const bf16x8*)(vts[cur] + (ht * 16 + l15) * VSS + kk * 32 + quad * 8);
        oacc[ht] = __builtin_amdgcn_mfma_f32_16x16x32_bf16(a, bb, oacc[ht], 0, 0, 0);
      }
    }
#pragma unroll
    for (int i = 0; i < 3; i++) {
      *(uint4*)(ks[nxt] + kr[i] * QSS + ko[i]) = kreg[i];
      *(uint4*)(vts[nxt] + vr[i] * VSS + vo[i]) = vreg[i];
    }
    __syncthreads();
  }
#pragma unroll
  for (int r = 0; r < 4; r++)
#pragma unroll
    for (int off = 1; off < 16; off <<= 1) li[r] += __shfl_xor(li[r], off, 16);
  u16* obase = o + (size_t)(b * 1024 + qt * 64 + w * 16) * 768 + h * 96;
#pragma unroll
  for (int r = 0; r < 4; r++) {
    float inv = 1.0f / li[r];
    int row = quad * 4 + r;
#pragma unroll
    for (int ht = 0; ht < 6; ht++)
      obase[(size_t)row * 768 + ht * 16 + l15] = f2bf(oacc[ht][r] * inv);
  }
}

// ---------------------------------------------------------------- launch
// d_out timeline: vtrans writes VT into d_out -> attn reads it -> Wo-GEMM
// overwrites d_out with y1 (VT dead) -> FFN2 reads res=y1, writes 1:1.
// ws: weights 14.2MB + bqkv + hb 25.2MB + qkvb 75.5MB ~= 115MB (proven).
extern "C" void kernel_launch(void* const* d_in, const int* in_sizes, int n_in,
                              void* d_out, int out_size, void* d_ws,
                              size_t ws_size, hipStream_t stream) {
  const float* x = (const float*)d_in[0];
  const float* gamma = (const float*)d_in[1];
  const float* beta = (const float*)d_in[2];
  const float* Wq = (const float*)d_in[3];
  const float* bq = (const float*)d_in[4];
  const float* Wk = (const float*)d_in[5];
  const float* bk = (const float*)d_in[6];
  const float* Wv = (const float*)d_in[7];
  const float* bv = (const float*)d_in[8];
  const float* Wo = (const float*)d_in[9];
  const float* bo = (const float*)d_in[10];
  const float* W1 = (const float*)d_in[11];
  const float* b1 = (const float*)d_in[12];
  const float* W2 = (const float*)d_in[13];
  const float* b2 = (const float*)d_in[14];
  float* out = (float*)d_out;

  char* ws = (char*)d_ws;
  size_t off = 0;
  auto alloc = [&](size_t elems) {
    u16* p = (u16*)(ws + off);
    off += elems * sizeof(u16);
    return p;
  };
  u16* WqT = alloc(768 * 768);   // WqT|WkT|WvT adjacent = fused [2304,768]
  u16* WkT = alloc(768 * 768);
  u16* WvT = alloc(768 * 768);
  u16* WoT = alloc(768 * 768);
  u16* W1T = alloc((size_t)768 * 3072);    // [3072,768]
  u16* W2T = alloc((size_t)3072 * 768);    // [768,3072]
  float* bqkv = (float*)(ws + off); off += 2304 * sizeof(float);
  u16* hb = alloc((size_t)16384 * 768);    // h -> attn_out -> h2
  u16* qkvb = alloc((size_t)16384 * 2304); // qkv -> f-chunks
  u16* vtb = (u16*)d_out;                  // VT lives in d_out until Wo

  // weight transposes fp32 -> bf16 [N,K]
  transpose4_k<<<dim3(24, 24, 4), 256, 0, stream>>>(Wq, Wk, Wv, Wo,
                                                    WqT, WkT, WvT, WoT);
  transpose_k<<<dim3(96, 24), 256, 0, stream>>>(W1, W1T, 768, 3072);
  transpose_k<<<dim3(24, 96), 256, 0, stream>>>(W2, W2T, 3072, 768);
  pack3_k<<<9, 256, 0, stream>>>(bq, bk, bv, bqkv);

  // LN1: x(fp32) -> h(bf16)
  ln_f32_k<<<16384, 256, 0, stream>>>(x, gamma, beta, hb);
  // fused QKV projection: [16384,768] @ [2304,768]^T -> qkvb [16384,2304]
  gemm_bt<0><<<dim3(128, 18), 256, 0, stream>>>(hb, WqT, bqkv, nullptr, qkvb,
                                                16384, 2304, 768, 768);
  // V cols -> VT [bh][96][1024] into d_out
  vtrans_k<<<dim3(3, 32, 128), 256, 0, stream>>>(qkvb, vtb);
  // attention: q,k from qkvb + VT from d_out -> dense attn-out in hb
  attn_k<<<dim3(16, 128), 256, 0, stream>>>(qkvb, vtb, hb);
  // y1(fp32, in d_out) = attn_out @ Wo + bo + x  (overwrites VT - dead)
  gemm_bt<4><<<dim3(128, 6), 256, 0, stream>>>(hb, WoT, bo, x, out,
                                               16384, 768, 768, 768);
  // h2 = LN(y1) -> hb (attn-out dead)
  ln_f32_k<<<16384, 256, 0, stream>>>(out, gamma, beta, hb);
  // FFN in 2 M-chunks of 8192 rows; f-chunk [8192,3072] bf16 fits qkvb
  for (int c = 0; c < 2; c++) {
    const u16* h2c = hb + (size_t)c * 8192 * 768;
    const float* y1c = out + (size_t)c * 8192 * 768;
    float* outc = out + (size_t)c * 8192 * 768;
    gemm_bt<2><<<dim3(64, 24), 256, 0, stream>>>(h2c, W1T, b1, nullptr, qkvb,
                                                 8192, 3072, 768, 768);
    gemm_bt<4><<<dim3(64, 6), 256, 0, stream>>>(qkvb, W2T, b2, y1c, outc,
                                                8192, 768, 3072, 3072);
  }
}